// Round 7
// baseline (483.658 us; speedup 1.0000x reference)
//
#include <hip/hip_runtime.h>
#include <math.h>

// Min-sum BP LDPC decoder, LDS-resident messages, degree-sorted checks.
// ONE dispatch total: setup (degree counting-sort + padded layout) is fused
// into bp_decode, recomputed per block in LDS. One block = one batch element;
// padded msg arena (~160 KB) lives in LDS.
//
// R8 post-mortem chain:
//  - R7: bench 453 vs R5's 367 with bp_decode IDENTICAL (181 us) -> the
//    harness charges ~28 us PER DISPATCH; 3 extra setup launches lost 85 us.
//    Dispatch count is a first-order cost here.
//  - R8: fuse everything -> single dispatch. Per-block in-LDS sort replaces
//    the setup kernel: wave-per-check BALLOT degree pass (coalesced row
//    reads; the old 1-block setup was issue-bound on uncoalesced scalar
//    loads = ~100+ us on 1 CU), LDS hist + counting-scatter + shuffle
//    prefix (~6 us total per block, all 256 blocks in parallel, mask is
//    L2-hot). Within-block scatter order nondeterministic: harmless,
//    equal-degree checks interchangeable, layout is block-private,
//    arithmetic untouched (bit-exact; R7 already validated this property).
//  - d_ws now entirely unused (no workspace hazards at all).
//  - Decode loop is BYTE-IDENTICAL to R5's (proven 180.6 us, conflicts
//    1.62e7 after odd-stride padding, zero spills, bit-exact pass).
//  - R6 lesson stands: never reorder the reference's FP arithmetic.

#define BLOCK 1024
#define NV    8192          // N variables
#define MC    4096          // M checks
#define NE    32768         // E edges (N * DV, DV=4)
#define VPT   (NV / BLOCK)  // 8 vars per thread
#define CPT   (MC / BLOCK)  // 4 checks per thread
#define NITER 10
#define ALPHA 0.8f
#define CLAMP 20.0f
#define MSGW  40896         // padded arena words (159.9 KB)

__device__ __forceinline__ int pad_stride(int d) { return d + 1 + (d & 1); }

// Single-pass check update, contiguous padded region, edge values in VGPRs.
template<int DMAX>
__device__ __forceinline__ void do_check(float* __restrict__ msg,
                                         int st, int d, float sgn, float pad)
{
    float x[DMAX];
    float min1 = pad, min2 = pad, prod = sgn;
#pragma unroll
    for (int j = 0; j < DMAX; ++j) {
        if (j >= d) break;
        x[j] = msg[st + j];
    }
#pragma unroll
    for (int j = 0; j < DMAX; ++j) {
        if (j >= d) break;
        prod = (x[j] < 0.0f) ? -prod : prod;            // sign(0)=+1 like ref
        const float a = fabsf(x[j]);
        min2 = __builtin_amdgcn_fmed3f(min1, min2, a);  // uses OLD min1
        min1 = fminf(min1, a);
    }
    const float vm1 = ALPHA * min1;
    const float vm2 = ALPHA * min2;
#pragma unroll
    for (int j = 0; j < DMAX; ++j) {
        if (j >= d) break;
        const float m = (fabsf(fabsf(x[j]) - min1) < 1e-9f) ? vm2 : vm1;  // ref tie rule
        const float v = m * prod;
        msg[st + j] = (x[j] < 0.0f) ? -v : v;           // excl_sign = prod * sign_j
    }
}

// Generic fallback for d > 16 (rare; re-reads LDS instead of caching).
__device__ void do_check_big(float* __restrict__ msg,
                             int st, int d, float sgn, float pad)
{
    float min1 = pad, min2 = pad, prod = sgn;
    for (int j = 0; j < d; ++j) {
        const float xx = msg[st + j];
        prod = (xx < 0.0f) ? -prod : prod;
        const float a = fabsf(xx);
        min2 = __builtin_amdgcn_fmed3f(min1, min2, a);
        min1 = fminf(min1, a);
    }
    const float vm1 = ALPHA * min1;
    const float vm2 = ALPHA * min2;
    for (int j = 0; j < d; ++j) {
        const float xx = msg[st + j];
        const float m  = (fabsf(fabsf(xx) - min1) < 1e-9f) ? vm2 : vm1;
        const float v  = m * prod;
        msg[st + j] = (xx < 0.0f) ? -v : v;
    }
}

__global__ __launch_bounds__(BLOCK) __attribute__((amdgpu_waves_per_eu(4, 4)))
void bp_decode(const float* __restrict__ syndrome,    // (B, M)
               const float* __restrict__ llr_g,       // (B, N)
               const int*   __restrict__ var_adj,     // (N, 4)
               const int*   __restrict__ var_idx,     // (E,)
               const int*   __restrict__ check_adj,   // (M, max_dc)
               const float* __restrict__ check_mask,  // (M, max_dc)
               int max_dc,
               float* __restrict__ out,               // marginals | hard | converged
               int B)
{
    __shared__ float msg[MSGW];  // padded arena; doubles as sort scratch early
    __shared__ float sh_e0;      // |vtc[edge 0]| snapshot for reference's pad
    __shared__ int   mism;

    const int b = blockIdx.x;
    const int t = threadIdx.x;
    const int lane = t & 63, wv = t >> 6;

    // ======== fused setup: degree counting-sort, block-private, in arena ====
    int* arena = (int*)msg;
    int* degR  = arena;            // [0   .. MC)   raw degree per check
    int* sSort = arena + MC;       // [MC  .. 2MC)  sorted: deg(6b) | c<<6
    int* rec1  = arena + 2 * MC;   // [2MC .. 3MC)  pbase(16b) | deg<<16
    int* rec2  = arena + 3 * MC;   // [3MC .. 4MC)  original check index
    int* hist  = arena + 4 * MC;   // [4MC .. 4MC+64)
    int* wsum  = arena + 4 * MC + 64;  // 16 words

    if (t < 64) hist[t] = 0;
    __syncthreads();

    // ---- pass 1: degrees via wave-per-check coalesced ballot ----
    for (int c = wv; c < MC; c += 16) {
        int d = 0;
        for (int j0 = 0; j0 < max_dc; j0 += 64) {
            const int j = j0 + lane;
            const float m = (j < max_dc) ? check_mask[(size_t)c * max_dc + j] : 0.0f;
            d += (int)__popcll(__ballot(m != 0.0f));
        }
        if (lane == 0) { degR[c] = d; atomicAdd(&hist[d & 63], 1); }
    }
    __syncthreads();

    // ---- bin prefix (exclusive starts) ----
    if (t == 0) {
        int s = 0;
        for (int i = 0; i < 64; ++i) { const int v = hist[i]; hist[i] = s; s += v; }
    }
    __syncthreads();

    // ---- counting-scatter into sorted order ----
#pragma unroll
    for (int k = 0; k < CPT; ++k) {
        const int c = t + k * BLOCK;
        const int d = degR[c];
        const int p = atomicAdd(&hist[d & 63], 1);
        sSort[p] = (d & 63) | (c << 6);
    }
    __syncthreads();

    // ---- padded prefix over sorted order; thread t owns 4t..4t+3 ----
    {
        int psz[CPT], pd[CPT], pc[CPT];
        int s = 0;
#pragma unroll
        for (int k = 0; k < CPT; ++k) {
            const int w = sSort[4 * t + k];
            const int d = w & 63;
            pd[k] = d; pc[k] = w >> 6;
            psz[k] = s;
            s += pad_stride(d);          // odd stride (bank-conflict fix)
        }
        int run = s;
#pragma unroll
        for (int off = 1; off < 64; off <<= 1) {
            const int n = __shfl_up(run, off, 64);
            if (lane >= off) run += n;
        }
        if (lane == 63) wsum[wv] = run;
        __syncthreads();
        if (t == 0) {
            int acc = 0;
            for (int w = 0; w < 16; ++w) { const int v = wsum[w]; wsum[w] = acc; acc += v; }
        }
        __syncthreads();
        const int tb = wsum[wv] + (run - s);   // exclusive base for this thread
#pragma unroll
        for (int k = 0; k < CPT; ++k) {
            const int i = 4 * t + k;
            rec1[i] = ((tb + psz[k]) & 0xFFFF) | (pd[k] << 16);
            rec2[i] = pc[k];
        }
    }
    __syncthreads();

    // ---- strided read-back of sorted records into registers ----
    int cst[CPT], dsb[CPT], stE[CPT];   // padded base; (deg<<1)|synbit; edge start
#pragma unroll
    for (int k = 0; k < CPT; ++k) {
        const int i = t + k * BLOCK;
        const int w = rec1[i];
        const int c = rec2[i];
        cst[k] = w & 0xFFFF;
        const int d  = w >> 16;
        const int sb = (syndrome[(size_t)b * MC + c] > 0.5f) ? 1 : 0;
        dsb[k] = (d << 1) | sb;
        stE[k] = check_adj[(size_t)c * max_dc];   // first edge (edges contiguous per check)
    }
    __syncthreads();

    // ---- build pos[e] (edge -> padded slot) in arena[0..NE) ----
    {
        int* posL = arena;
#pragma unroll
        for (int k = 0; k < CPT; ++k) {
            const int d  = dsb[k] >> 1;
            const int pb = cst[k];
            const int st = stE[k];
            for (int j = 0; j < d; ++j)
                posL[st + j] = pb + j;
        }
    }
    __syncthreads();

    // ---- edge-0 owner (for reference's pad = |vtc[0]| + 1e6) ----
    const int  v0  = var_idx[0];
    const int4 r0  = ((const int4*)var_adj)[v0];
    const int  j0  = (r0.y == 0) ? 1 : (r0.z == 0) ? 2 : (r0.w == 0) ? 3 : 0;
    const bool own = (t == (v0 & (BLOCK - 1)));
    const int  k0  = v0 >> 10;            // v0 / BLOCK

    // ---- var-side padded slots + LLRs into registers ----
    int   vs[VPT][4];
    float llr[VPT];
    {
        const int* posL = arena;
#pragma unroll
        for (int k = 0; k < VPT; ++k) {
            const int v = t + k * BLOCK;
            const int4 a = ((const int4*)var_adj)[v];   // var degree is exactly 4
            vs[k][0] = posL[a.x]; vs[k][1] = posL[a.y];
            vs[k][2] = posL[a.z]; vs[k][3] = posL[a.w];
            llr[k] = llr_g[(size_t)b * NV + v];
        }
    }
    __syncthreads();

    for (int e = t; e < MSGW; e += BLOCK) msg[e] = 0.0f;   // ctv0 = 0
    __syncthreads();

    // ======== decode loop (BYTE-IDENTICAL to R5) ========
    for (int it = 0; it < NITER; ++it) {
        // ---- variable phase: msg(ctv) -> msg(vtc), in place ----
#pragma unroll
        for (int k = 0; k < VPT; ++k) {
            const float c0 = msg[vs[k][0]];
            const float c1 = msg[vs[k][1]];
            const float c2 = msg[vs[k][2]];
            const float c3 = msg[vs[k][3]];
            const float tot  = ((c0 + c1) + c2) + c3;   // reference sum order
            const float bse  = llr[k] + tot;
            const float o0 = __builtin_amdgcn_fmed3f(bse - c0, -CLAMP, CLAMP);
            const float o1 = __builtin_amdgcn_fmed3f(bse - c1, -CLAMP, CLAMP);
            const float o2 = __builtin_amdgcn_fmed3f(bse - c2, -CLAMP, CLAMP);
            const float o3 = __builtin_amdgcn_fmed3f(bse - c3, -CLAMP, CLAMP);
            msg[vs[k][0]] = o0;
            msg[vs[k][1]] = o1;
            msg[vs[k][2]] = o2;
            msg[vs[k][3]] = o3;
            if (own && k == k0) {
                const float vv = (j0 == 0) ? o0 : (j0 == 1) ? o1
                               : (j0 == 2) ? o2 : o3;
                sh_e0 = fabsf(vv) + 1.0e6f;
            }
        }
        __syncthreads();
        const float pad = sh_e0;

        // ---- check phase: contiguous padded regions, in place ----
#pragma unroll
        for (int k = 0; k < CPT; ++k) {
            const int   d   = dsb[k] >> 1;
            const float sgn = (dsb[k] & 1) ? -1.0f : 1.0f;
            const int   st  = cst[k];
            if (d <= 8)       do_check<8>(msg, st, d, sgn, pad);
            else if (d <= 12) do_check<12>(msg, st, d, sgn, pad);
            else if (d <= 16) do_check<16>(msg, st, d, sgn, pad);
            else              do_check_big(msg, st, d, sgn, pad);
        }
        __syncthreads();
    }

    // ---- finale: marginals, hard decisions, convergence ----
    float marg[VPT], hard[VPT];
#pragma unroll
    for (int k = 0; k < VPT; ++k) {
        const float c0 = msg[vs[k][0]];
        const float c1 = msg[vs[k][1]];
        const float c2 = msg[vs[k][2]];
        const float c3 = msg[vs[k][3]];
        const float tot = ((c0 + c1) + c2) + c3;
        const float tl  = llr[k] + tot;
        const float mg  = 1.0f / (1.0f + expf(tl));   // sigmoid(-tl)
        marg[k] = mg;
        hard[k] = (mg > 0.5f) ? 1.0f : 0.0f;
    }
    if (t == 0) mism = 0;
    __syncthreads();   // all ctv reads done; safe to overwrite msg

    const size_t BN = (size_t)B * NV;
#pragma unroll
    for (int k = 0; k < VPT; ++k) {
        const int v = t + k * BLOCK;
        out[(size_t)b * NV + v]      = marg[k];        // output 0: marginals
        out[BN + (size_t)b * NV + v] = hard[k];        // output 1: hard_decision
        const float h = hard[k];                       // scatter hard bit to edges
        msg[vs[k][0]] = h;
        msg[vs[k][1]] = h;
        msg[vs[k][2]] = h;
        msg[vs[k][3]] = h;
    }
    __syncthreads();

    // syn_hat[c] = parity over the check's edges' hard bits; converged iff == syndrome
#pragma unroll
    for (int k = 0; k < CPT; ++k) {
        const int d  = dsb[k] >> 1;
        const int sb = dsb[k] & 1;
        const int st = cst[k];
        int par = 0;
        for (int j = 0; j < d; ++j)
            par ^= (msg[st + j] != 0.0f) ? 1 : 0;
        if (par != sb) mism = 1;   // benign race: all writers store 1
    }
    __syncthreads();
    if (t == 0) out[2 * BN + b] = mism ? 0.0f : 1.0f;  // output 2: converged
}

extern "C" void kernel_launch(void* const* d_in, const int* in_sizes, int n_in,
                              void* d_out, int out_size, void* d_ws, size_t ws_size,
                              hipStream_t stream) {
    const float* syndrome   = (const float*)d_in[0];
    const float* llr        = (const float*)d_in[1];
    const int*   var_adj    = (const int*)d_in[2];
    // d_in[3] var_adj_mask: all ones (DV=4 exact) — unused
    const int*   check_adj  = (const int*)d_in[4];
    const float* check_mask = (const float*)d_in[5];
    const int*   var_idx    = (const int*)d_in[6];
    // d_in[7] pcm_dense — unused
    float* out = (float*)d_out;
    (void)d_ws; (void)ws_size;   // workspace unused: zero hazard

    const int B      = in_sizes[0] / MC;      // 256
    const int max_dc = in_sizes[4] / MC;

    bp_decode<<<B, BLOCK, 0, stream>>>(syndrome, llr, var_adj, var_idx,
                                       check_adj, check_mask, max_dc, out, B);
}

// Round 8
// 379.957 us; speedup vs baseline: 1.2729x; 1.2729x over previous
//
#include <hip/hip_runtime.h>
#include <math.h>

// Min-sum BP LDPC decoder, LDS-resident messages, degree-sorted checks.
// One block = one batch element; padded msg arena (~160 KB) lives in LDS.
//
// R9 = R5's proven two-dispatch structure (setup_sort 1-block + bp_decode;
// total 367.6, bp 180.6, conflicts 1.62e7, zero spills) + latency/VALU trims:
//  - Harness model (R7/R8 calibration): fixed floor ~165 us + ~28 us per
//    extra dispatch. R8's fused per-block sort cost +137 us GPU -> reverted.
//  - VAR-PHASE READ BATCHING: issue all 32 ds_reads into cv[8][4] before any
//    compute/write. Thread-disjoint slots => value-identical (sum order
//    untouched); hides ~120cyc LDS latency that the old read4/sum/write4
//    per-var chain exposed. Uses ~32 extra VGPRs (budget 128 at 4 waves/EU).
//  - XOR-SIGN PARITY (bit-exact): vtc = clip(base-c) can never be -0.0 (RN:
//    x-y=+0 when equal; ctv0=+0; hard bits >= 0), so sign-bit == reference's
//    (x>=0 ? +1 : -1). excl_sign*|m| == bit-OR of sign into positive m
//    (multiply by +-1.0 is exact).
//  - fabs CACHE: a[j] from the scan loop reused in the write loop.
//  - Reference tie rule KEPT VERBATIM: (fabs(a[j]-min1) < 1e-9) ? min2 : min1.
//    (R6 lesson: argmin shortcut / any FP reorder of the reference = fail.)

#define BLOCK 1024
#define NV    8192          // N variables
#define MC    4096          // M checks
#define NE    32768         // E edges (N * DV, DV=4)
#define VPT   (NV / BLOCK)  // 8 vars per thread
#define CPT   (MC / BLOCK)  // 4 checks per thread
#define NITER 10
#define ALPHA 0.8f
#define CLAMP 20.0f
#define MSGW  40896         // padded arena words (159.9 KB)
#define SGNB  0x80000000

// ws layout (ints), 32 KB:
//  [0 .. MC)   : pbase(16b) | deg<<16   (degree-sorted order)
//  [MC .. 2MC) : original check index   (for syndrome + check_adj lookup)

__device__ __forceinline__ int pad_stride(int d) { return d + 1 + (d & 1); }

// ---------------- setup: counting-sort + padded prefix (R5's, proven) -------
__global__ __launch_bounds__(BLOCK)
void setup_sort(const float* __restrict__ check_mask,
                const int*   __restrict__ check_adj,
                int max_dc, int* __restrict__ ws)
{
    __shared__ int hist[64], cbase[64], wsum[16];
    __shared__ int sdeg[MC];
    const int t = threadIdx.x;
    if (t < 64) hist[t] = 0;
    __syncthreads();
    int deg[CPT];
#pragma unroll
    for (int k = 0; k < CPT; ++k) {
        const int c = t + k * BLOCK;
        int d = 0;
        for (int j = 0; j < max_dc; ++j)
            d += (check_mask[(size_t)c * max_dc + j] != 0.0f) ? 1 : 0;
        deg[k] = d;
        atomicAdd(&hist[d & 63], 1);
    }
    __syncthreads();
    if (t == 0) {
        int s = 0;
        for (int i = 0; i < 64; ++i) { cbase[i] = s; s += hist[i]; }
    }
    __syncthreads();
#pragma unroll
    for (int k = 0; k < CPT; ++k) {
        const int pos = atomicAdd(&cbase[deg[k] & 63], 1);
        sdeg[pos]    = deg[k];
        ws[MC + pos] = t + k * BLOCK;
    }
    __syncthreads();
    int psz[CPT];
    int s = 0;
#pragma unroll
    for (int k = 0; k < CPT; ++k) {
        const int d = sdeg[4 * t + k];
        psz[k] = s;
        s += pad_stride(d);             // odd stride (bank-conflict fix)
    }
    const int lane = t & 63, wv = t >> 6;
    int run = s;
#pragma unroll
    for (int off = 1; off < 64; off <<= 1) {
        const int n = __shfl_up(run, off, 64);
        if (lane >= off) run += n;
    }
    if (lane == 63) wsum[wv] = run;
    __syncthreads();
    if (t == 0) {
        int acc = 0;
        for (int w = 0; w < 16; ++w) { const int v = wsum[w]; wsum[w] = acc; acc += v; }
    }
    __syncthreads();
    const int tb = wsum[wv] + (run - s);
#pragma unroll
    for (int k = 0; k < CPT; ++k) {
        const int i = 4 * t + k;
        ws[i] = ((tb + psz[k]) & 0xFFFF) | (sdeg[i] << 16);
    }
}

// Single-pass check update, contiguous padded region, edge values in VGPRs.
// ssb = syndrome sign bit (bit31). Bit-exact vs reference (see header).
template<int DMAX>
__device__ __forceinline__ void do_check(float* __restrict__ msg,
                                         int st, int d, int ssb, float pad)
{
    float x[DMAX], a[DMAX];
    float min1 = pad, min2 = pad;
    int sb = ssb;
#pragma unroll
    for (int j = 0; j < DMAX; ++j) {
        if (j >= d) break;
        x[j] = msg[st + j];
    }
#pragma unroll
    for (int j = 0; j < DMAX; ++j) {
        if (j >= d) break;
        sb ^= __float_as_int(x[j]);                     // sign parity (no -0.0)
        a[j] = fabsf(x[j]);
        min2 = __builtin_amdgcn_fmed3f(min1, min2, a[j]);  // uses OLD min1
        min1 = fminf(min1, a[j]);
    }
    const float vm1 = ALPHA * min1;
    const float vm2 = ALPHA * min2;
#pragma unroll
    for (int j = 0; j < DMAX; ++j) {
        if (j >= d) break;
        const float m = (fabsf(a[j] - min1) < 1e-9f) ? vm2 : vm1;  // REF tie rule
        const int  ob = __float_as_int(m) | ((sb ^ __float_as_int(x[j])) & SGNB);
        msg[st + j] = __int_as_float(ob);               // excl_sign * alpha * excl_min
    }
}

// Generic fallback for d > 16 (rare; re-reads LDS instead of caching).
__device__ void do_check_big(float* __restrict__ msg,
                             int st, int d, int ssb, float pad)
{
    float min1 = pad, min2 = pad;
    int sb = ssb;
    for (int j = 0; j < d; ++j) {
        const float xx = msg[st + j];
        sb ^= __float_as_int(xx);
        const float aa = fabsf(xx);
        min2 = __builtin_amdgcn_fmed3f(min1, min2, aa);
        min1 = fminf(min1, aa);
    }
    const float vm1 = ALPHA * min1;
    const float vm2 = ALPHA * min2;
    for (int j = 0; j < d; ++j) {
        const float xx = msg[st + j];
        const float m  = (fabsf(fabsf(xx) - min1) < 1e-9f) ? vm2 : vm1;
        const int  ob  = __float_as_int(m) | ((sb ^ __float_as_int(xx)) & SGNB);
        msg[st + j] = __int_as_float(ob);
    }
}

__global__ __launch_bounds__(BLOCK) __attribute__((amdgpu_waves_per_eu(4, 4)))
void bp_decode(const float* __restrict__ syndrome,    // (B, M)
               const float* __restrict__ llr_g,       // (B, N)
               const int*   __restrict__ var_adj,     // (N, 4)
               const int*   __restrict__ var_idx,     // (E,)
               const int*   __restrict__ check_adj,   // (M, max_dc)
               int max_dc,
               const int*   __restrict__ ws,          // sorted check info
               float* __restrict__ out,               // marginals | hard | converged
               int B)
{
    __shared__ float msg[MSGW];  // padded arena, in-place ctv/vtc
    __shared__ float sh_e0;      // |vtc[edge 0]| snapshot for reference's pad
    __shared__ int   mism;

    const int b = blockIdx.x;
    const int t = threadIdx.x;

    // ---- load sorted-check info; build pos[e] in LDS (aliasing msg) ----
    int cst[CPT], dsb[CPT];   // padded base; (deg<<1) | syndrome_bit
    {
        int* posL = (int*)msg;
#pragma unroll
        for (int k = 0; k < CPT; ++k) {
            const int i = t + k * BLOCK;
            const int w = ws[i];
            const int c = ws[MC + i];
            const int pb = w & 0xFFFF;
            const int d  = w >> 16;
            cst[k] = pb;
            const int sb = (syndrome[(size_t)b * MC + c] > 0.5f) ? 1 : 0;
            dsb[k] = (d << 1) | sb;
            const int st = check_adj[(size_t)c * max_dc];  // first edge (contiguous)
            for (int j = 0; j < d; ++j)
                posL[st + j] = pb + j;
        }
    }
    __syncthreads();

    // ---- edge-0 owner (for reference's pad = |vtc[0]| + 1e6) ----
    const int  v0  = var_idx[0];
    const int4 r0  = ((const int4*)var_adj)[v0];
    const int  j0  = (r0.y == 0) ? 1 : (r0.z == 0) ? 2 : (r0.w == 0) ? 3 : 0;
    const bool own = (t == (v0 & (BLOCK - 1)));
    const int  k0  = v0 >> 10;            // v0 / BLOCK

    // ---- var-side padded slots + LLRs into registers ----
    int   vs[VPT][4];
    float llr[VPT];
    {
        const int* posL = (const int*)msg;
#pragma unroll
        for (int k = 0; k < VPT; ++k) {
            const int v = t + k * BLOCK;
            const int4 a = ((const int4*)var_adj)[v];   // var degree is exactly 4
            vs[k][0] = posL[a.x]; vs[k][1] = posL[a.y];
            vs[k][2] = posL[a.z]; vs[k][3] = posL[a.w];
            llr[k] = llr_g[(size_t)b * NV + v];
        }
    }
    __syncthreads();

    for (int e = t; e < MSGW; e += BLOCK) msg[e] = 0.0f;   // ctv0 = 0
    __syncthreads();

    for (int it = 0; it < NITER; ++it) {
        // ---- variable phase: batch ALL reads, then compute+write ----
        // (thread-disjoint slots; identical values & sum order as R5)
        float cv[VPT][4];
#pragma unroll
        for (int k = 0; k < VPT; ++k) {
            cv[k][0] = msg[vs[k][0]];
            cv[k][1] = msg[vs[k][1]];
            cv[k][2] = msg[vs[k][2]];
            cv[k][3] = msg[vs[k][3]];
        }
#pragma unroll
        for (int k = 0; k < VPT; ++k) {
            const float tot = ((cv[k][0] + cv[k][1]) + cv[k][2]) + cv[k][3];
            const float bse = llr[k] + tot;              // reference sum order
            const float o0 = __builtin_amdgcn_fmed3f(bse - cv[k][0], -CLAMP, CLAMP);
            const float o1 = __builtin_amdgcn_fmed3f(bse - cv[k][1], -CLAMP, CLAMP);
            const float o2 = __builtin_amdgcn_fmed3f(bse - cv[k][2], -CLAMP, CLAMP);
            const float o3 = __builtin_amdgcn_fmed3f(bse - cv[k][3], -CLAMP, CLAMP);
            msg[vs[k][0]] = o0;
            msg[vs[k][1]] = o1;
            msg[vs[k][2]] = o2;
            msg[vs[k][3]] = o3;
            if (own && k == k0) {
                const float vv = (j0 == 0) ? o0 : (j0 == 1) ? o1
                               : (j0 == 2) ? o2 : o3;
                sh_e0 = fabsf(vv) + 1.0e6f;
            }
        }
        __syncthreads();
        const float pad = sh_e0;

        // ---- check phase: contiguous padded regions, in place ----
#pragma unroll
        for (int k = 0; k < CPT; ++k) {
            const int d   = dsb[k] >> 1;
            const int ssb = (dsb[k] & 1) << 31;
            const int st  = cst[k];
            if (d <= 8)       do_check<8>(msg, st, d, ssb, pad);
            else if (d <= 12) do_check<12>(msg, st, d, ssb, pad);
            else if (d <= 16) do_check<16>(msg, st, d, ssb, pad);
            else              do_check_big(msg, st, d, ssb, pad);
        }
        __syncthreads();
    }

    // ---- finale: marginals, hard decisions, convergence ----
    float marg[VPT], hard[VPT];
#pragma unroll
    for (int k = 0; k < VPT; ++k) {
        const float c0 = msg[vs[k][0]];
        const float c1 = msg[vs[k][1]];
        const float c2 = msg[vs[k][2]];
        const float c3 = msg[vs[k][3]];
        const float tot = ((c0 + c1) + c2) + c3;
        const float tl  = llr[k] + tot;
        const float mg  = 1.0f / (1.0f + expf(tl));   // sigmoid(-tl)
        marg[k] = mg;
        hard[k] = (mg > 0.5f) ? 1.0f : 0.0f;
    }
    if (t == 0) mism = 0;
    __syncthreads();   // all ctv reads done; safe to overwrite msg

    const size_t BN = (size_t)B * NV;
#pragma unroll
    for (int k = 0; k < VPT; ++k) {
        const int v = t + k * BLOCK;
        out[(size_t)b * NV + v]      = marg[k];        // output 0: marginals
        out[BN + (size_t)b * NV + v] = hard[k];        // output 1: hard_decision
        const float h = hard[k];                       // scatter hard bit to edges
        msg[vs[k][0]] = h;
        msg[vs[k][1]] = h;
        msg[vs[k][2]] = h;
        msg[vs[k][3]] = h;
    }
    __syncthreads();

    // syn_hat[c] = parity over the check's edges' hard bits; converged iff == syndrome
#pragma unroll
    for (int k = 0; k < CPT; ++k) {
        const int d  = dsb[k] >> 1;
        const int sb = dsb[k] & 1;
        const int st = cst[k];
        int par = 0;
        for (int j = 0; j < d; ++j)
            par ^= (msg[st + j] != 0.0f) ? 1 : 0;
        if (par != sb) mism = 1;   // benign race: all writers store 1
    }
    __syncthreads();
    if (t == 0) out[2 * BN + b] = mism ? 0.0f : 1.0f;  // output 2: converged
}

extern "C" void kernel_launch(void* const* d_in, const int* in_sizes, int n_in,
                              void* d_out, int out_size, void* d_ws, size_t ws_size,
                              hipStream_t stream) {
    const float* syndrome   = (const float*)d_in[0];
    const float* llr        = (const float*)d_in[1];
    const int*   var_adj    = (const int*)d_in[2];
    // d_in[3] var_adj_mask: all ones (DV=4 exact) — unused
    const int*   check_adj  = (const int*)d_in[4];
    const float* check_mask = (const float*)d_in[5];
    const int*   var_idx    = (const int*)d_in[6];
    // d_in[7] pcm_dense — unused
    float* out = (float*)d_out;
    int*   ws  = (int*)d_ws;    // needs 2*MC ints = 32 KB (R1/R5-proven size)

    const int B      = in_sizes[0] / MC;      // 256
    const int max_dc = in_sizes[4] / MC;

    setup_sort<<<1, BLOCK, 0, stream>>>(check_mask, check_adj, max_dc, ws);
    bp_decode<<<B, BLOCK, 0, stream>>>(syndrome, llr, var_adj, var_idx,
                                       check_adj, max_dc, ws, out, B);
}

// Round 9
// 357.947 us; speedup vs baseline: 1.3512x; 1.0615x over previous
//
#include <hip/hip_runtime.h>
#include <math.h>

// Min-sum BP LDPC decoder, LDS-resident messages, degree-sorted checks.
// One block = one batch element; padded msg arena (~160 KB) lives in LDS.
//
// R10 = R5's proven structure (two dispatches; bp 180.6 us, 64 VGPR, zero
// spills, conflicts 1.62e7) + register-neutral trims only:
//  - HARD CONSTRAINT (R3/R9 post-mortems): the allocator pins 64 VGPRs for
//    this kernel regardless of launch_bounds/waves_per_eu hints; any live
//    state beyond R5's spills to scratch (R9: WRITE 16->43 MB, bp +34 us).
//    So: no read batching, no per-edge tables, no fabs cache.
//  - ITER-0 SPECIALIZATION (bit-exact): ctv==0 => vtc = clip(llr), same
//    value on all 4 edges of a var. Iter 0 becomes write-only (no LDS
//    reads), and the arena zero-fill is dropped entirely (check phase
//    never reads pad gaps; every edge slot is written in iter 0).
//  - XOR-SIGN PARITY (bit-exact; hardware-validated by R9's PASS): sign
//    product via xor of raw sign bits; vtc = clip(base-c) can never be
//    -0.0 (RN: x-y=+0 when equal; ctv0=+0), so sign-bit == reference's
//    (x>=0 ? +1 : -1); applying the sign by bit-OR onto the positive
//    magnitude is exact (== multiply by +-1.0).
//  - Reference tie rule VERBATIM: (fabs(|x|-min1) < 1e-9) ? min2 : min1.
//  - R6 lesson stands: never reorder the reference's FP arithmetic
//    (var-phase sum order = adjacency order, kept exactly).
//  - Harness model (R7/R8): fixed floor ~165 us + ~28 us/dispatch; the
//    1-block setup_sort dispatch (~22 us incl. overhead) is the minimum.

#define BLOCK 1024
#define NV    8192          // N variables
#define MC    4096          // M checks
#define NE    32768         // E edges (N * DV, DV=4)
#define VPT   (NV / BLOCK)  // 8 vars per thread
#define CPT   (MC / BLOCK)  // 4 checks per thread
#define NITER 10
#define ALPHA 0.8f
#define CLAMP 20.0f
#define MSGW  40896         // padded arena words (159.9 KB)
#define SGNB  0x80000000

// ws layout (ints), 32 KB:
//  [0 .. MC)   : pbase(16b) | deg<<16   (degree-sorted order)
//  [MC .. 2MC) : original check index   (for syndrome + check_adj lookup)

__device__ __forceinline__ int pad_stride(int d) { return d + 1 + (d & 1); }

// ---------------- setup: counting-sort + padded prefix (R5's, proven) -------
__global__ __launch_bounds__(BLOCK)
void setup_sort(const float* __restrict__ check_mask,
                const int*   __restrict__ check_adj,
                int max_dc, int* __restrict__ ws)
{
    __shared__ int hist[64], cbase[64], wsum[16];
    __shared__ int sdeg[MC];
    const int t = threadIdx.x;
    if (t < 64) hist[t] = 0;
    __syncthreads();
    int deg[CPT];
#pragma unroll
    for (int k = 0; k < CPT; ++k) {
        const int c = t + k * BLOCK;
        int d = 0;
        for (int j = 0; j < max_dc; ++j)
            d += (check_mask[(size_t)c * max_dc + j] != 0.0f) ? 1 : 0;
        deg[k] = d;
        atomicAdd(&hist[d & 63], 1);
    }
    __syncthreads();
    if (t == 0) {
        int s = 0;
        for (int i = 0; i < 64; ++i) { cbase[i] = s; s += hist[i]; }
    }
    __syncthreads();
#pragma unroll
    for (int k = 0; k < CPT; ++k) {
        const int pos = atomicAdd(&cbase[deg[k] & 63], 1);
        sdeg[pos]    = deg[k];
        ws[MC + pos] = t + k * BLOCK;
    }
    __syncthreads();
    int psz[CPT];
    int s = 0;
#pragma unroll
    for (int k = 0; k < CPT; ++k) {
        const int d = sdeg[4 * t + k];
        psz[k] = s;
        s += pad_stride(d);             // odd stride (bank-conflict fix)
    }
    const int lane = t & 63, wv = t >> 6;
    int run = s;
#pragma unroll
    for (int off = 1; off < 64; off <<= 1) {
        const int n = __shfl_up(run, off, 64);
        if (lane >= off) run += n;
    }
    if (lane == 63) wsum[wv] = run;
    __syncthreads();
    if (t == 0) {
        int acc = 0;
        for (int w = 0; w < 16; ++w) { const int v = wsum[w]; wsum[w] = acc; acc += v; }
    }
    __syncthreads();
    const int tb = wsum[wv] + (run - s);
#pragma unroll
    for (int k = 0; k < CPT; ++k) {
        const int i = 4 * t + k;
        ws[i] = ((tb + psz[k]) & 0xFFFF) | (sdeg[i] << 16);
    }
}

// Single-pass check update, contiguous padded region, edge values in VGPRs.
// ssb = syndrome sign bit (bit31). Bit-exact vs reference (validated R9).
template<int DMAX>
__device__ __forceinline__ void do_check(float* __restrict__ msg,
                                         int st, int d, int ssb, float pad)
{
    float x[DMAX];
    float min1 = pad, min2 = pad;
    int sb = ssb;
#pragma unroll
    for (int j = 0; j < DMAX; ++j) {
        if (j >= d) break;
        x[j] = msg[st + j];
    }
#pragma unroll
    for (int j = 0; j < DMAX; ++j) {
        if (j >= d) break;
        sb ^= __float_as_int(x[j]);                     // sign parity (no -0.0)
        const float a = fabsf(x[j]);
        min2 = __builtin_amdgcn_fmed3f(min1, min2, a);  // uses OLD min1
        min1 = fminf(min1, a);
    }
    const float vm1 = ALPHA * min1;
    const float vm2 = ALPHA * min2;
#pragma unroll
    for (int j = 0; j < DMAX; ++j) {
        if (j >= d) break;
        const float m = (fabsf(fabsf(x[j]) - min1) < 1e-9f) ? vm2 : vm1;  // REF tie rule
        const int  ob = __float_as_int(m) | ((sb ^ __float_as_int(x[j])) & SGNB);
        msg[st + j] = __int_as_float(ob);               // excl_sign * alpha * excl_min
    }
}

// Generic fallback for d > 16 (rare; re-reads LDS instead of caching).
__device__ void do_check_big(float* __restrict__ msg,
                             int st, int d, int ssb, float pad)
{
    float min1 = pad, min2 = pad;
    int sb = ssb;
    for (int j = 0; j < d; ++j) {
        const float xx = msg[st + j];
        sb ^= __float_as_int(xx);
        const float aa = fabsf(xx);
        min2 = __builtin_amdgcn_fmed3f(min1, min2, aa);
        min1 = fminf(min1, aa);
    }
    const float vm1 = ALPHA * min1;
    const float vm2 = ALPHA * min2;
    for (int j = 0; j < d; ++j) {
        const float xx = msg[st + j];
        const float m  = (fabsf(fabsf(xx) - min1) < 1e-9f) ? vm2 : vm1;
        const int  ob  = __float_as_int(m) | ((sb ^ __float_as_int(xx)) & SGNB);
        msg[st + j] = __int_as_float(ob);
    }
}

__global__ __launch_bounds__(BLOCK) __attribute__((amdgpu_waves_per_eu(4, 4)))
void bp_decode(const float* __restrict__ syndrome,    // (B, M)
               const float* __restrict__ llr_g,       // (B, N)
               const int*   __restrict__ var_adj,     // (N, 4)
               const int*   __restrict__ var_idx,     // (E,)
               const int*   __restrict__ check_adj,   // (M, max_dc)
               int max_dc,
               const int*   __restrict__ ws,          // sorted check info
               float* __restrict__ out,               // marginals | hard | converged
               int B)
{
    __shared__ float msg[MSGW];  // padded arena, in-place ctv/vtc
    __shared__ float sh_e0;      // |vtc[edge 0]| snapshot for reference's pad
    __shared__ int   mism;

    const int b = blockIdx.x;
    const int t = threadIdx.x;

    // ---- load sorted-check info; build pos[e] in LDS (aliasing msg) ----
    int cst[CPT], dsb[CPT];   // padded base; (deg<<1) | syndrome_bit
    {
        int* posL = (int*)msg;
#pragma unroll
        for (int k = 0; k < CPT; ++k) {
            const int i = t + k * BLOCK;
            const int w = ws[i];
            const int c = ws[MC + i];
            const int pb = w & 0xFFFF;
            const int d  = w >> 16;
            cst[k] = pb;
            const int sb = (syndrome[(size_t)b * MC + c] > 0.5f) ? 1 : 0;
            dsb[k] = (d << 1) | sb;
            const int st = check_adj[(size_t)c * max_dc];  // first edge (contiguous)
            for (int j = 0; j < d; ++j)
                posL[st + j] = pb + j;
        }
    }
    __syncthreads();

    // ---- edge-0 owner (for reference's pad = |vtc[0]| + 1e6) ----
    const int  v0  = var_idx[0];
    const int4 r0  = ((const int4*)var_adj)[v0];
    const int  j0  = (r0.y == 0) ? 1 : (r0.z == 0) ? 2 : (r0.w == 0) ? 3 : 0;
    const bool own = (t == (v0 & (BLOCK - 1)));
    const int  k0  = v0 >> 10;            // v0 / BLOCK

    // ---- var-side padded slots + LLRs into registers ----
    int   vs[VPT][4];
    float llr[VPT];
    {
        const int* posL = (const int*)msg;
#pragma unroll
        for (int k = 0; k < VPT; ++k) {
            const int v = t + k * BLOCK;
            const int4 a = ((const int4*)var_adj)[v];   // var degree is exactly 4
            vs[k][0] = posL[a.x]; vs[k][1] = posL[a.y];
            vs[k][2] = posL[a.z]; vs[k][3] = posL[a.w];
            llr[k] = llr_g[(size_t)b * NV + v];
        }
    }
    __syncthreads();   // posL reads done; msg may now be overwritten (no zero-fill:
                       // iter 0 writes every edge slot; pad gaps are never read)

    for (int it = 0; it < NITER; ++it) {
        if (it == 0) {
            // ---- iter-0 var phase: ctv==0 -> vtc = clip(llr), write-only ----
#pragma unroll
            for (int k = 0; k < VPT; ++k) {
                const float o = __builtin_amdgcn_fmed3f(llr[k], -CLAMP, CLAMP);
                msg[vs[k][0]] = o;
                msg[vs[k][1]] = o;
                msg[vs[k][2]] = o;
                msg[vs[k][3]] = o;
                if (own && k == k0) sh_e0 = fabsf(o) + 1.0e6f;
            }
        } else {
            // ---- variable phase: msg(ctv) -> msg(vtc), in place ----
#pragma unroll
            for (int k = 0; k < VPT; ++k) {
                const float c0 = msg[vs[k][0]];
                const float c1 = msg[vs[k][1]];
                const float c2 = msg[vs[k][2]];
                const float c3 = msg[vs[k][3]];
                const float tot  = ((c0 + c1) + c2) + c3;   // reference sum order
                const float bse  = llr[k] + tot;
                const float o0 = __builtin_amdgcn_fmed3f(bse - c0, -CLAMP, CLAMP);
                const float o1 = __builtin_amdgcn_fmed3f(bse - c1, -CLAMP, CLAMP);
                const float o2 = __builtin_amdgcn_fmed3f(bse - c2, -CLAMP, CLAMP);
                const float o3 = __builtin_amdgcn_fmed3f(bse - c3, -CLAMP, CLAMP);
                msg[vs[k][0]] = o0;
                msg[vs[k][1]] = o1;
                msg[vs[k][2]] = o2;
                msg[vs[k][3]] = o3;
                if (own && k == k0) {
                    const float vv = (j0 == 0) ? o0 : (j0 == 1) ? o1
                                   : (j0 == 2) ? o2 : o3;
                    sh_e0 = fabsf(vv) + 1.0e6f;
                }
            }
        }
        __syncthreads();
        const float pad = sh_e0;

        // ---- check phase: contiguous padded regions, in place ----
#pragma unroll
        for (int k = 0; k < CPT; ++k) {
            const int d   = dsb[k] >> 1;
            const int ssb = (dsb[k] & 1) << 31;
            const int st  = cst[k];
            if (d <= 8)       do_check<8>(msg, st, d, ssb, pad);
            else if (d <= 12) do_check<12>(msg, st, d, ssb, pad);
            else if (d <= 16) do_check<16>(msg, st, d, ssb, pad);
            else              do_check_big(msg, st, d, ssb, pad);
        }
        __syncthreads();
    }

    // ---- finale: marginals, hard decisions, convergence ----
    float marg[VPT], hard[VPT];
#pragma unroll
    for (int k = 0; k < VPT; ++k) {
        const float c0 = msg[vs[k][0]];
        const float c1 = msg[vs[k][1]];
        const float c2 = msg[vs[k][2]];
        const float c3 = msg[vs[k][3]];
        const float tot = ((c0 + c1) + c2) + c3;
        const float tl  = llr[k] + tot;
        const float mg  = 1.0f / (1.0f + expf(tl));   // sigmoid(-tl)
        marg[k] = mg;
        hard[k] = (mg > 0.5f) ? 1.0f : 0.0f;
    }
    if (t == 0) mism = 0;
    __syncthreads();   // all ctv reads done; safe to overwrite msg

    const size_t BN = (size_t)B * NV;
#pragma unroll
    for (int k = 0; k < VPT; ++k) {
        const int v = t + k * BLOCK;
        out[(size_t)b * NV + v]      = marg[k];        // output 0: marginals
        out[BN + (size_t)b * NV + v] = hard[k];        // output 1: hard_decision
        const float h = hard[k];                       // scatter hard bit to edges
        msg[vs[k][0]] = h;
        msg[vs[k][1]] = h;
        msg[vs[k][2]] = h;
        msg[vs[k][3]] = h;
    }
    __syncthreads();

    // syn_hat[c] = parity over the check's edges' hard bits; converged iff == syndrome
#pragma unroll
    for (int k = 0; k < CPT; ++k) {
        const int d  = dsb[k] >> 1;
        const int sb = dsb[k] & 1;
        const int st = cst[k];
        int par = 0;
        for (int j = 0; j < d; ++j)
            par ^= (msg[st + j] != 0.0f) ? 1 : 0;
        if (par != sb) mism = 1;   // benign race: all writers store 1
    }
    __syncthreads();
    if (t == 0) out[2 * BN + b] = mism ? 0.0f : 1.0f;  // output 2: converged
}

extern "C" void kernel_launch(void* const* d_in, const int* in_sizes, int n_in,
                              void* d_out, int out_size, void* d_ws, size_t ws_size,
                              hipStream_t stream) {
    const float* syndrome   = (const float*)d_in[0];
    const float* llr        = (const float*)d_in[1];
    const int*   var_adj    = (const int*)d_in[2];
    // d_in[3] var_adj_mask: all ones (DV=4 exact) — unused
    const int*   check_adj  = (const int*)d_in[4];
    const float* check_mask = (const float*)d_in[5];
    const int*   var_idx    = (const int*)d_in[6];
    // d_in[7] pcm_dense — unused
    float* out = (float*)d_out;
    int*   ws  = (int*)d_ws;    // needs 2*MC ints = 32 KB (R1/R5-proven size)

    const int B      = in_sizes[0] / MC;      // 256
    const int max_dc = in_sizes[4] / MC;

    setup_sort<<<1, BLOCK, 0, stream>>>(check_mask, check_adj, max_dc, ws);
    bp_decode<<<B, BLOCK, 0, stream>>>(syndrome, llr, var_adj, var_idx,
                                       check_adj, max_dc, ws, out, B);
}

// Round 10
// 335.673 us; speedup vs baseline: 1.4409x; 1.0664x over previous
//
#include <hip/hip_runtime.h>
#include <math.h>

// Min-sum BP LDPC decoder, LDS-resident messages, degree-sorted checks.
// One block = one batch element; padded msg arena (~160 KB) lives in LDS.
//
// R11 = R10 (bp 170.4 us: odd-stride padding + iter-0 specialization +
// xor-sign parity, all bit-exact, 64 VGPR, zero spills) + mask-free checks:
//  - EXACT-DEGREE DISPATCH: after degree sort, d is ~wave-uniform. The old
//    do_check<DMAX> ranged ladder pays a v_cmp+exec-mask per unrolled j
//    (3 loops x DMAX) because d is per-lane. Exact variants do_check_x<D>
//    (D = 4..12, ~95% of Poisson(8) mass) have NO per-j checks; the if-tree
//    on d is wave-coherent (sorted) so non-matching levels cost ~1 cmp+skip.
//    d<=3 / d<=16 keep the ranged fallback; d>16 generic; d==0 no-op (big
//    with d=0 executes nothing).
//  - E0-PAD HOIST: reference pad = |vtc[edge0]|+1e6. Owner thread re-reads
//    its own write once per iteration (LDS same-thread RAW is ordered)
//    instead of an (own && k==k0) compare chain in every var k-step.
//    e0slot = posL[0], captured during the pos-table window.
//  - NITER loop #pragma unroll 1 + iter 0 peeled: one copy of the dispatch
//    tree per k-step keeps I-cache footprint small.
//  - HARD CONSTRAINTS (R3/R9): allocator pins 64 VGPRs; everything here is
//    register-neutral. (R6): never reorder reference FP arithmetic — var
//    sum order, tie rule (fabs(|x|-min1)<1e-9), clamp semantics verbatim.
//  - Harness model (R7/R8): ~165 us fixed floor + ~22-28 us per dispatch;
//    two dispatches is the proven minimum (R8's fused setup cost +137 us).

#define BLOCK 1024
#define NV    8192          // N variables
#define MC    4096          // M checks
#define NE    32768         // E edges (N * DV, DV=4)
#define VPT   (NV / BLOCK)  // 8 vars per thread
#define CPT   (MC / BLOCK)  // 4 checks per thread
#define NITER 10
#define ALPHA 0.8f
#define CLAMP 20.0f
#define MSGW  40896         // padded arena words (159.9 KB)
#define SGNB  0x80000000

// ws layout (ints), 32 KB:
//  [0 .. MC)   : pbase(16b) | deg<<16   (degree-sorted order)
//  [MC .. 2MC) : original check index   (for syndrome + check_adj lookup)

__device__ __forceinline__ int pad_stride(int d) { return d + 1 + (d & 1); }

// ---------------- setup: counting-sort + padded prefix (R5's, proven) -------
__global__ __launch_bounds__(BLOCK)
void setup_sort(const float* __restrict__ check_mask,
                const int*   __restrict__ check_adj,
                int max_dc, int* __restrict__ ws)
{
    __shared__ int hist[64], cbase[64], wsum[16];
    __shared__ int sdeg[MC];
    const int t = threadIdx.x;
    if (t < 64) hist[t] = 0;
    __syncthreads();
    int deg[CPT];
#pragma unroll
    for (int k = 0; k < CPT; ++k) {
        const int c = t + k * BLOCK;
        int d = 0;
        for (int j = 0; j < max_dc; ++j)
            d += (check_mask[(size_t)c * max_dc + j] != 0.0f) ? 1 : 0;
        deg[k] = d;
        atomicAdd(&hist[d & 63], 1);
    }
    __syncthreads();
    if (t == 0) {
        int s = 0;
        for (int i = 0; i < 64; ++i) { cbase[i] = s; s += hist[i]; }
    }
    __syncthreads();
#pragma unroll
    for (int k = 0; k < CPT; ++k) {
        const int pos = atomicAdd(&cbase[deg[k] & 63], 1);
        sdeg[pos]    = deg[k];
        ws[MC + pos] = t + k * BLOCK;
    }
    __syncthreads();
    int psz[CPT];
    int s = 0;
#pragma unroll
    for (int k = 0; k < CPT; ++k) {
        const int d = sdeg[4 * t + k];
        psz[k] = s;
        s += pad_stride(d);             // odd stride (bank-conflict fix)
    }
    const int lane = t & 63, wv = t >> 6;
    int run = s;
#pragma unroll
    for (int off = 1; off < 64; off <<= 1) {
        const int n = __shfl_up(run, off, 64);
        if (lane >= off) run += n;
    }
    if (lane == 63) wsum[wv] = run;
    __syncthreads();
    if (t == 0) {
        int acc = 0;
        for (int w = 0; w < 16; ++w) { const int v = wsum[w]; wsum[w] = acc; acc += v; }
    }
    __syncthreads();
    const int tb = wsum[wv] + (run - s);
#pragma unroll
    for (int k = 0; k < CPT; ++k) {
        const int i = 4 * t + k;
        ws[i] = ((tb + psz[k]) & 0xFFFF) | (sdeg[i] << 16);
    }
}

// Exact-degree check update: no per-j degree checks at all.
// ssb = syndrome sign bit (bit31). Bit-exact vs reference (validated R9/R10).
template<int D>
__device__ __forceinline__ void do_check_x(float* __restrict__ msg,
                                           int st, int ssb, float pad)
{
    float x[D];
    float min1 = pad, min2 = pad;
    int sb = ssb;
#pragma unroll
    for (int j = 0; j < D; ++j)
        x[j] = msg[st + j];
#pragma unroll
    for (int j = 0; j < D; ++j) {
        sb ^= __float_as_int(x[j]);                     // sign parity (no -0.0)
        const float a = fabsf(x[j]);
        min2 = __builtin_amdgcn_fmed3f(min1, min2, a);  // uses OLD min1
        min1 = fminf(min1, a);
    }
    const float vm1 = ALPHA * min1;
    const float vm2 = ALPHA * min2;
#pragma unroll
    for (int j = 0; j < D; ++j) {
        const float m = (fabsf(fabsf(x[j]) - min1) < 1e-9f) ? vm2 : vm1;  // REF tie rule
        const int  ob = __float_as_int(m) | ((sb ^ __float_as_int(x[j])) & SGNB);
        msg[st + j] = __int_as_float(ob);               // excl_sign * alpha * excl_min
    }
}

// Ranged fallback (per-j break) for uncommon degrees.
template<int DMAX>
__device__ __forceinline__ void do_check(float* __restrict__ msg,
                                         int st, int d, int ssb, float pad)
{
    float x[DMAX];
    float min1 = pad, min2 = pad;
    int sb = ssb;
#pragma unroll
    for (int j = 0; j < DMAX; ++j) {
        if (j >= d) break;
        x[j] = msg[st + j];
    }
#pragma unroll
    for (int j = 0; j < DMAX; ++j) {
        if (j >= d) break;
        sb ^= __float_as_int(x[j]);
        const float a = fabsf(x[j]);
        min2 = __builtin_amdgcn_fmed3f(min1, min2, a);
        min1 = fminf(min1, a);
    }
    const float vm1 = ALPHA * min1;
    const float vm2 = ALPHA * min2;
#pragma unroll
    for (int j = 0; j < DMAX; ++j) {
        if (j >= d) break;
        const float m = (fabsf(fabsf(x[j]) - min1) < 1e-9f) ? vm2 : vm1;
        const int  ob = __float_as_int(m) | ((sb ^ __float_as_int(x[j])) & SGNB);
        msg[st + j] = __int_as_float(ob);
    }
}

// Generic fallback for d > 16 (rare; re-reads LDS; d==0 is a no-op).
__device__ void do_check_big(float* __restrict__ msg,
                             int st, int d, int ssb, float pad)
{
    float min1 = pad, min2 = pad;
    int sb = ssb;
    for (int j = 0; j < d; ++j) {
        const float xx = msg[st + j];
        sb ^= __float_as_int(xx);
        const float aa = fabsf(xx);
        min2 = __builtin_amdgcn_fmed3f(min1, min2, aa);
        min1 = fminf(min1, aa);
    }
    const float vm1 = ALPHA * min1;
    const float vm2 = ALPHA * min2;
    for (int j = 0; j < d; ++j) {
        const float xx = msg[st + j];
        const float m  = (fabsf(fabsf(xx) - min1) < 1e-9f) ? vm2 : vm1;
        const int  ob  = __float_as_int(m) | ((sb ^ __float_as_int(xx)) & SGNB);
        msg[st + j] = __int_as_float(ob);
    }
}

// Check phase for one k-step: exact-degree tree (wave-coherent after sort).
__device__ __forceinline__ void check_dispatch(float* __restrict__ msg,
                                               int st, int d, int ssb, float pad)
{
    if      (d == 8)  do_check_x<8>(msg, st, ssb, pad);
    else if (d == 7)  do_check_x<7>(msg, st, ssb, pad);
    else if (d == 9)  do_check_x<9>(msg, st, ssb, pad);
    else if (d == 6)  do_check_x<6>(msg, st, ssb, pad);
    else if (d == 10) do_check_x<10>(msg, st, ssb, pad);
    else if (d == 5)  do_check_x<5>(msg, st, ssb, pad);
    else if (d == 11) do_check_x<11>(msg, st, ssb, pad);
    else if (d == 12) do_check_x<12>(msg, st, ssb, pad);
    else if (d == 4)  do_check_x<4>(msg, st, ssb, pad);
    else if (d <= 3)  do_check<3>(msg, st, d, ssb, pad);
    else if (d <= 16) do_check<16>(msg, st, d, ssb, pad);
    else              do_check_big(msg, st, d, ssb, pad);
}

__global__ __launch_bounds__(BLOCK) __attribute__((amdgpu_waves_per_eu(4, 4)))
void bp_decode(const float* __restrict__ syndrome,    // (B, M)
               const float* __restrict__ llr_g,       // (B, N)
               const int*   __restrict__ var_adj,     // (N, 4)
               const int*   __restrict__ var_idx,     // (E,)
               const int*   __restrict__ check_adj,   // (M, max_dc)
               int max_dc,
               const int*   __restrict__ ws,          // sorted check info
               float* __restrict__ out,               // marginals | hard | converged
               int B)
{
    __shared__ float msg[MSGW];  // padded arena, in-place ctv/vtc
    __shared__ float sh_e0;      // |vtc[edge 0]| snapshot for reference's pad
    __shared__ int   mism;

    const int b = blockIdx.x;
    const int t = threadIdx.x;

    // ---- load sorted-check info; build pos[e] in LDS (aliasing msg) ----
    int cst[CPT], dsb[CPT];   // padded base; (deg<<1) | syndrome_bit
    {
        int* posL = (int*)msg;
#pragma unroll
        for (int k = 0; k < CPT; ++k) {
            const int i = t + k * BLOCK;
            const int w = ws[i];
            const int c = ws[MC + i];
            const int pb = w & 0xFFFF;
            const int d  = w >> 16;
            cst[k] = pb;
            const int sb = (syndrome[(size_t)b * MC + c] > 0.5f) ? 1 : 0;
            dsb[k] = (d << 1) | sb;
            const int st = check_adj[(size_t)c * max_dc];  // first edge (contiguous)
            for (int j = 0; j < d; ++j)
                posL[st + j] = pb + j;
        }
    }
    __syncthreads();

    // ---- edge-0 owner info (reference's pad = |vtc[0]| + 1e6) ----
    const int  v0     = var_idx[0];
    const bool own    = (t == (v0 & (BLOCK - 1)));   // thread that writes edge 0
    const int  e0slot = ((const int*)msg)[0];        // posL[0]: padded slot of edge 0

    // ---- var-side padded slots + LLRs into registers ----
    int   vs[VPT][4];
    float llr[VPT];
    {
        const int* posL = (const int*)msg;
#pragma unroll
        for (int k = 0; k < VPT; ++k) {
            const int v = t + k * BLOCK;
            const int4 a = ((const int4*)var_adj)[v];   // var degree is exactly 4
            vs[k][0] = posL[a.x]; vs[k][1] = posL[a.y];
            vs[k][2] = posL[a.z]; vs[k][3] = posL[a.w];
            llr[k] = llr_g[(size_t)b * NV + v];
        }
    }
    __syncthreads();   // posL reads done; msg may now be overwritten (no zero-fill:
                       // iter 0 writes every edge slot; pad gaps are never read)

    // ======== iter 0 (peeled): ctv==0 -> vtc = clip(llr), write-only ========
#pragma unroll
    for (int k = 0; k < VPT; ++k) {
        const float o = __builtin_amdgcn_fmed3f(llr[k], -CLAMP, CLAMP);
        msg[vs[k][0]] = o;
        msg[vs[k][1]] = o;
        msg[vs[k][2]] = o;
        msg[vs[k][3]] = o;
    }
    if (own) sh_e0 = fabsf(msg[e0slot]) + 1.0e6f;   // own write, same-thread RAW
    __syncthreads();
    {
        const float pad = sh_e0;
#pragma unroll
        for (int k = 0; k < CPT; ++k)
            check_dispatch(msg, cst[k], dsb[k] >> 1, (dsb[k] & 1) << 31, pad);
    }
    __syncthreads();

    // ======== iters 1..NITER-1 ========
#pragma unroll 1
    for (int it = 1; it < NITER; ++it) {
        // ---- variable phase: msg(ctv) -> msg(vtc), in place ----
#pragma unroll
        for (int k = 0; k < VPT; ++k) {
            const float c0 = msg[vs[k][0]];
            const float c1 = msg[vs[k][1]];
            const float c2 = msg[vs[k][2]];
            const float c3 = msg[vs[k][3]];
            const float tot  = ((c0 + c1) + c2) + c3;   // reference sum order
            const float bse  = llr[k] + tot;
            msg[vs[k][0]] = __builtin_amdgcn_fmed3f(bse - c0, -CLAMP, CLAMP);
            msg[vs[k][1]] = __builtin_amdgcn_fmed3f(bse - c1, -CLAMP, CLAMP);
            msg[vs[k][2]] = __builtin_amdgcn_fmed3f(bse - c2, -CLAMP, CLAMP);
            msg[vs[k][3]] = __builtin_amdgcn_fmed3f(bse - c3, -CLAMP, CLAMP);
        }
        if (own) sh_e0 = fabsf(msg[e0slot]) + 1.0e6f;   // own write, ordered
        __syncthreads();
        const float pad = sh_e0;

        // ---- check phase: contiguous padded regions, in place ----
#pragma unroll
        for (int k = 0; k < CPT; ++k)
            check_dispatch(msg, cst[k], dsb[k] >> 1, (dsb[k] & 1) << 31, pad);
        __syncthreads();
    }

    // ---- finale: marginals, hard decisions, convergence ----
    float marg[VPT], hard[VPT];
#pragma unroll
    for (int k = 0; k < VPT; ++k) {
        const float c0 = msg[vs[k][0]];
        const float c1 = msg[vs[k][1]];
        const float c2 = msg[vs[k][2]];
        const float c3 = msg[vs[k][3]];
        const float tot = ((c0 + c1) + c2) + c3;
        const float tl  = llr[k] + tot;
        const float mg  = 1.0f / (1.0f + expf(tl));   // sigmoid(-tl)
        marg[k] = mg;
        hard[k] = (mg > 0.5f) ? 1.0f : 0.0f;
    }
    if (t == 0) mism = 0;
    __syncthreads();   // all ctv reads done; safe to overwrite msg

    const size_t BN = (size_t)B * NV;
#pragma unroll
    for (int k = 0; k < VPT; ++k) {
        const int v = t + k * BLOCK;
        out[(size_t)b * NV + v]      = marg[k];        // output 0: marginals
        out[BN + (size_t)b * NV + v] = hard[k];        // output 1: hard_decision
        const float h = hard[k];                       // scatter hard bit to edges
        msg[vs[k][0]] = h;
        msg[vs[k][1]] = h;
        msg[vs[k][2]] = h;
        msg[vs[k][3]] = h;
    }
    __syncthreads();

    // syn_hat[c] = parity over the check's edges' hard bits; converged iff == syndrome
#pragma unroll
    for (int k = 0; k < CPT; ++k) {
        const int d  = dsb[k] >> 1;
        const int sb = dsb[k] & 1;
        const int st = cst[k];
        int par = 0;
        for (int j = 0; j < d; ++j)
            par ^= (msg[st + j] != 0.0f) ? 1 : 0;
        if (par != sb) mism = 1;   // benign race: all writers store 1
    }
    __syncthreads();
    if (t == 0) out[2 * BN + b] = mism ? 0.0f : 1.0f;  // output 2: converged
}

extern "C" void kernel_launch(void* const* d_in, const int* in_sizes, int n_in,
                              void* d_out, int out_size, void* d_ws, size_t ws_size,
                              hipStream_t stream) {
    const float* syndrome   = (const float*)d_in[0];
    const float* llr        = (const float*)d_in[1];
    const int*   var_adj    = (const int*)d_in[2];
    // d_in[3] var_adj_mask: all ones (DV=4 exact) — unused
    const int*   check_adj  = (const int*)d_in[4];
    const float* check_mask = (const float*)d_in[5];
    const int*   var_idx    = (const int*)d_in[6];
    // d_in[7] pcm_dense — unused
    float* out = (float*)d_out;
    int*   ws  = (int*)d_ws;    // needs 2*MC ints = 32 KB (R1/R5-proven size)

    const int B      = in_sizes[0] / MC;      // 256
    const int max_dc = in_sizes[4] / MC;

    setup_sort<<<1, BLOCK, 0, stream>>>(check_mask, check_adj, max_dc, ws);
    bp_decode<<<B, BLOCK, 0, stream>>>(syndrome, llr, var_adj, var_idx,
                                       check_adj, max_dc, ws, out, B);
}

// Round 11
// 334.919 us; speedup vs baseline: 1.4441x; 1.0023x over previous
//
#include <hip/hip_runtime.h>
#include <math.h>

// Min-sum BP LDPC decoder, LDS-resident messages, degree-sorted checks.
// One block = one batch element; padded msg arena (~160 KB) lives in LDS.
//
// R12 = R11 (bp 148 us: odd-stride pad + iter-0 peel + xor-sign + exact-degree
// dispatch; VALUBusy 49.7->36.2%) + VECTORIZED CHECK-PHASE LDS:
//  - STRIDE ≡ 2 (mod 4): check i gets region of s(d) = d + ((2-(d&3))&3)
//    words. Even bases => 8B-aligned => ds_read_b64/ds_write_b64 pairs halve
//    check-phase LDS instruction count (the LDS pipe is ~50% of cycles).
//    Within uniform-degree runs lane bases step s ≡ 2 mod 4 => orbit covers
//    all 16 even bank residues => 4 words/bank per b64 instruction =
//    bandwidth-optimal (s ≡ 0 mod 4 would be 16-way; excluded by rule).
//    Space: E[waste]=1.5/check, total ~38.9k words = same as R5's odd rule,
//    27 sigma under the 40896-word cap.
//  - BYTE-PRESHIFTED OFFSETS (R6's safe ingredient alone): all msg addresses
//    stored <<2 at init; every ds op is reg-direct, no per-op v_lshl_add.
//  - Odd-D tail: one b32 read/write (no garbage reads; pad gaps never read).
//  - Everything bit-exact: pure layout/access-width change; var sum order,
//    tie rule, clamp, xor-sign (R9/R10-validated) untouched.
//  - HARD CONSTRAINTS: 64-VGPR allocator pin (R3/R9) — all changes register-
//    neutral; never reorder reference FP arithmetic (R6); two dispatches
//    minimum (R7/R8 harness model: ~165 us floor + ~22-28 us/dispatch).

#define BLOCK 1024
#define NV    8192          // N variables
#define MC    4096          // M checks
#define NE    32768         // E edges (N * DV, DV=4)
#define VPT   (NV / BLOCK)  // 8 vars per thread
#define CPT   (MC / BLOCK)  // 4 checks per thread
#define NITER 10
#define ALPHA 0.8f
#define CLAMP 20.0f
#define MSGW  40896         // padded arena words (159.9 KB)
#define SGNB  0x80000000

// ws layout (ints), 32 KB:
//  [0 .. MC)   : pbase(16b) | deg<<16   (degree-sorted order)
//  [MC .. 2MC) : original check index   (for syndrome + check_adj lookup)

// stride: smallest s >= d with s ≡ 2 (mod 4)  [even base + bank spreading]
__device__ __forceinline__ int pad_stride(int d) { return d + ((2 - (d & 3)) & 3); }

// ---------------- setup: counting-sort + padded prefix ----------------
__global__ __launch_bounds__(BLOCK)
void setup_sort(const float* __restrict__ check_mask,
                const int*   __restrict__ check_adj,
                int max_dc, int* __restrict__ ws)
{
    __shared__ int hist[64], cbase[64], wsum[16];
    __shared__ int sdeg[MC];
    const int t = threadIdx.x;
    if (t < 64) hist[t] = 0;
    __syncthreads();
    int deg[CPT];
#pragma unroll
    for (int k = 0; k < CPT; ++k) {
        const int c = t + k * BLOCK;
        int d = 0;
        for (int j = 0; j < max_dc; ++j)
            d += (check_mask[(size_t)c * max_dc + j] != 0.0f) ? 1 : 0;
        deg[k] = d;
        atomicAdd(&hist[d & 63], 1);
    }
    __syncthreads();
    if (t == 0) {
        int s = 0;
        for (int i = 0; i < 64; ++i) { cbase[i] = s; s += hist[i]; }
    }
    __syncthreads();
#pragma unroll
    for (int k = 0; k < CPT; ++k) {
        const int pos = atomicAdd(&cbase[deg[k] & 63], 1);
        sdeg[pos]    = deg[k];
        ws[MC + pos] = t + k * BLOCK;
    }
    __syncthreads();
    int psz[CPT];
    int s = 0;
#pragma unroll
    for (int k = 0; k < CPT; ++k) {
        const int d = sdeg[4 * t + k];
        psz[k] = s;
        s += pad_stride(d);             // even, ≡2 mod 4
    }
    const int lane = t & 63, wv = t >> 6;
    int run = s;
#pragma unroll
    for (int off = 1; off < 64; off <<= 1) {
        const int n = __shfl_up(run, off, 64);
        if (lane >= off) run += n;
    }
    if (lane == 63) wsum[wv] = run;
    __syncthreads();
    if (t == 0) {
        int acc = 0;
        for (int w = 0; w < 16; ++w) { const int v = wsum[w]; wsum[w] = acc; acc += v; }
    }
    __syncthreads();
    const int tb = wsum[wv] + (run - s);
#pragma unroll
    for (int k = 0; k < CPT; ++k) {
        const int i = 4 * t + k;
        ws[i] = ((tb + psz[k]) & 0xFFFF) | (sdeg[i] << 16);
    }
}

// Exact-degree check update, b64 vectorized, byte-base addressing.
// ssb = syndrome sign bit (bit31). Bit-exact vs reference (validated R9-R11).
template<int D>
__device__ __forceinline__ void do_check_x(char* __restrict__ mb,
                                           int stB, int ssb, float pad)
{
    float x[D];
    constexpr int P = D / 2;
#pragma unroll
    for (int p = 0; p < P; ++p) {
        const float2 r = *(const float2*)(mb + stB + 8 * p);
        x[2 * p]     = r.x;
        x[2 * p + 1] = r.y;
    }
    if constexpr (D & 1)
        x[D - 1] = *(const float*)(mb + stB + 4 * (D - 1));

    float min1 = pad, min2 = pad;
    int sb = ssb;
#pragma unroll
    for (int j = 0; j < D; ++j) {
        sb ^= __float_as_int(x[j]);                     // sign parity (no -0.0)
        const float a = fabsf(x[j]);
        min2 = __builtin_amdgcn_fmed3f(min1, min2, a);  // uses OLD min1
        min1 = fminf(min1, a);
    }
    const float vm1 = ALPHA * min1;
    const float vm2 = ALPHA * min2;
#pragma unroll
    for (int p = 0; p < P; ++p) {
        const int j0 = 2 * p, j1 = 2 * p + 1;
        const float m0 = (fabsf(fabsf(x[j0]) - min1) < 1e-9f) ? vm2 : vm1;  // REF tie rule
        const float m1 = (fabsf(fabsf(x[j1]) - min1) < 1e-9f) ? vm2 : vm1;
        float2 w;
        w.x = __int_as_float(__float_as_int(m0) | ((sb ^ __float_as_int(x[j0])) & SGNB));
        w.y = __int_as_float(__float_as_int(m1) | ((sb ^ __float_as_int(x[j1])) & SGNB));
        *(float2*)(mb + stB + 8 * p) = w;
    }
    if constexpr (D & 1) {
        const int jt = D - 1;
        const float mt = (fabsf(fabsf(x[jt]) - min1) < 1e-9f) ? vm2 : vm1;
        *(float*)(mb + stB + 4 * jt) =
            __int_as_float(__float_as_int(mt) | ((sb ^ __float_as_int(x[jt])) & SGNB));
    }
}

// Ranged fallback (per-j break, b32) for uncommon degrees.
template<int DMAX>
__device__ __forceinline__ void do_check(char* __restrict__ mb,
                                         int stB, int d, int ssb, float pad)
{
    float x[DMAX];
    float min1 = pad, min2 = pad;
    int sb = ssb;
#pragma unroll
    for (int j = 0; j < DMAX; ++j) {
        if (j >= d) break;
        x[j] = *(const float*)(mb + stB + 4 * j);
    }
#pragma unroll
    for (int j = 0; j < DMAX; ++j) {
        if (j >= d) break;
        sb ^= __float_as_int(x[j]);
        const float a = fabsf(x[j]);
        min2 = __builtin_amdgcn_fmed3f(min1, min2, a);
        min1 = fminf(min1, a);
    }
    const float vm1 = ALPHA * min1;
    const float vm2 = ALPHA * min2;
#pragma unroll
    for (int j = 0; j < DMAX; ++j) {
        if (j >= d) break;
        const float m = (fabsf(fabsf(x[j]) - min1) < 1e-9f) ? vm2 : vm1;
        *(float*)(mb + stB + 4 * j) =
            __int_as_float(__float_as_int(m) | ((sb ^ __float_as_int(x[j])) & SGNB));
    }
}

// Generic fallback for d > 16 (rare; re-reads LDS; d==0 is a no-op).
__device__ void do_check_big(char* __restrict__ mb,
                             int stB, int d, int ssb, float pad)
{
    float min1 = pad, min2 = pad;
    int sb = ssb;
    for (int j = 0; j < d; ++j) {
        const float xx = *(const float*)(mb + stB + 4 * j);
        sb ^= __float_as_int(xx);
        const float aa = fabsf(xx);
        min2 = __builtin_amdgcn_fmed3f(min1, min2, aa);
        min1 = fminf(min1, aa);
    }
    const float vm1 = ALPHA * min1;
    const float vm2 = ALPHA * min2;
    for (int j = 0; j < d; ++j) {
        const float xx = *(const float*)(mb + stB + 4 * j);
        const float m  = (fabsf(fabsf(xx) - min1) < 1e-9f) ? vm2 : vm1;
        *(float*)(mb + stB + 4 * j) =
            __int_as_float(__float_as_int(m) | ((sb ^ __float_as_int(xx)) & SGNB));
    }
}

// Check phase for one k-step: exact-degree tree (wave-coherent after sort).
__device__ __forceinline__ void check_dispatch(char* __restrict__ mb,
                                               int stB, int d, int ssb, float pad)
{
    if      (d == 8)  do_check_x<8>(mb, stB, ssb, pad);
    else if (d == 7)  do_check_x<7>(mb, stB, ssb, pad);
    else if (d == 9)  do_check_x<9>(mb, stB, ssb, pad);
    else if (d == 6)  do_check_x<6>(mb, stB, ssb, pad);
    else if (d == 10) do_check_x<10>(mb, stB, ssb, pad);
    else if (d == 5)  do_check_x<5>(mb, stB, ssb, pad);
    else if (d == 11) do_check_x<11>(mb, stB, ssb, pad);
    else if (d == 12) do_check_x<12>(mb, stB, ssb, pad);
    else if (d == 4)  do_check_x<4>(mb, stB, ssb, pad);
    else if (d <= 3)  do_check<3>(mb, stB, d, ssb, pad);
    else if (d <= 16) do_check<16>(mb, stB, d, ssb, pad);
    else              do_check_big(mb, stB, d, ssb, pad);
}

__global__ __launch_bounds__(BLOCK) __attribute__((amdgpu_waves_per_eu(4, 4)))
void bp_decode(const float* __restrict__ syndrome,    // (B, M)
               const float* __restrict__ llr_g,       // (B, N)
               const int*   __restrict__ var_adj,     // (N, 4)
               const int*   __restrict__ var_idx,     // (E,)
               const int*   __restrict__ check_adj,   // (M, max_dc)
               int max_dc,
               const int*   __restrict__ ws,          // sorted check info
               float* __restrict__ out,               // marginals | hard | converged
               int B)
{
    __shared__ float msg[MSGW];  // padded arena, in-place ctv/vtc
    __shared__ float sh_e0;      // |vtc[edge 0]| snapshot for reference's pad
    __shared__ int   mism;

    const int b = blockIdx.x;
    const int t = threadIdx.x;
    char* mb = (char*)msg;

    // ---- load sorted-check info; build pos[e] in LDS (aliasing msg) ----
    int cstB[CPT], dsb[CPT];   // byte base; (deg<<1) | syndrome_bit
    {
        int* posL = (int*)msg;
#pragma unroll
        for (int k = 0; k < CPT; ++k) {
            const int i = t + k * BLOCK;
            const int w = ws[i];
            const int c = ws[MC + i];
            const int pb = w & 0xFFFF;
            const int d  = w >> 16;
            cstB[k] = pb << 2;
            const int sb = (syndrome[(size_t)b * MC + c] > 0.5f) ? 1 : 0;
            dsb[k] = (d << 1) | sb;
            const int st = check_adj[(size_t)c * max_dc];  // first edge (contiguous)
            for (int j = 0; j < d; ++j)
                posL[st + j] = pb + j;
        }
    }
    __syncthreads();

    // ---- edge-0 owner info (reference's pad = |vtc[0]| + 1e6) ----
    const int  v0  = var_idx[0];
    const bool own = (t == (v0 & (BLOCK - 1)));      // thread that writes edge 0
    const int  e0B = ((const int*)msg)[0] << 2;      // posL[0] as byte offset

    // ---- var-side padded slots (byte offsets) + LLRs into registers ----
    int   vsB[VPT][4];
    float llr[VPT];
    {
        const int* posL = (const int*)msg;
#pragma unroll
        for (int k = 0; k < VPT; ++k) {
            const int v = t + k * BLOCK;
            const int4 a = ((const int4*)var_adj)[v];   // var degree is exactly 4
            vsB[k][0] = posL[a.x] << 2; vsB[k][1] = posL[a.y] << 2;
            vsB[k][2] = posL[a.z] << 2; vsB[k][3] = posL[a.w] << 2;
            llr[k] = llr_g[(size_t)b * NV + v];
        }
    }
    __syncthreads();   // posL reads done; msg may now be overwritten (no zero-fill:
                       // iter 0 writes every edge slot; pad gaps are never read)

    // ======== iter 0 (peeled): ctv==0 -> vtc = clip(llr), write-only ========
#pragma unroll
    for (int k = 0; k < VPT; ++k) {
        const float o = __builtin_amdgcn_fmed3f(llr[k], -CLAMP, CLAMP);
        *(float*)(mb + vsB[k][0]) = o;
        *(float*)(mb + vsB[k][1]) = o;
        *(float*)(mb + vsB[k][2]) = o;
        *(float*)(mb + vsB[k][3]) = o;
    }
    if (own) sh_e0 = fabsf(*(const float*)(mb + e0B)) + 1.0e6f;  // own write, RAW-ordered
    __syncthreads();
    {
        const float pad = sh_e0;
#pragma unroll
        for (int k = 0; k < CPT; ++k)
            check_dispatch(mb, cstB[k], dsb[k] >> 1, (dsb[k] & 1) << 31, pad);
    }
    __syncthreads();

    // ======== iters 1..NITER-1 ========
#pragma unroll 1
    for (int it = 1; it < NITER; ++it) {
        // ---- variable phase: msg(ctv) -> msg(vtc), in place ----
#pragma unroll
        for (int k = 0; k < VPT; ++k) {
            const float c0 = *(const float*)(mb + vsB[k][0]);
            const float c1 = *(const float*)(mb + vsB[k][1]);
            const float c2 = *(const float*)(mb + vsB[k][2]);
            const float c3 = *(const float*)(mb + vsB[k][3]);
            const float tot  = ((c0 + c1) + c2) + c3;   // reference sum order
            const float bse  = llr[k] + tot;
            *(float*)(mb + vsB[k][0]) = __builtin_amdgcn_fmed3f(bse - c0, -CLAMP, CLAMP);
            *(float*)(mb + vsB[k][1]) = __builtin_amdgcn_fmed3f(bse - c1, -CLAMP, CLAMP);
            *(float*)(mb + vsB[k][2]) = __builtin_amdgcn_fmed3f(bse - c2, -CLAMP, CLAMP);
            *(float*)(mb + vsB[k][3]) = __builtin_amdgcn_fmed3f(bse - c3, -CLAMP, CLAMP);
        }
        if (own) sh_e0 = fabsf(*(const float*)(mb + e0B)) + 1.0e6f;   // own write, ordered
        __syncthreads();
        const float pad = sh_e0;

        // ---- check phase: contiguous padded regions, b64 pairs ----
#pragma unroll
        for (int k = 0; k < CPT; ++k)
            check_dispatch(mb, cstB[k], dsb[k] >> 1, (dsb[k] & 1) << 31, pad);
        __syncthreads();
    }

    // ---- finale: marginals, hard decisions, convergence ----
    float marg[VPT], hard[VPT];
#pragma unroll
    for (int k = 0; k < VPT; ++k) {
        const float c0 = *(const float*)(mb + vsB[k][0]);
        const float c1 = *(const float*)(mb + vsB[k][1]);
        const float c2 = *(const float*)(mb + vsB[k][2]);
        const float c3 = *(const float*)(mb + vsB[k][3]);
        const float tot = ((c0 + c1) + c2) + c3;
        const float tl  = llr[k] + tot;
        const float mg  = 1.0f / (1.0f + expf(tl));   // sigmoid(-tl)
        marg[k] = mg;
        hard[k] = (mg > 0.5f) ? 1.0f : 0.0f;
    }
    if (t == 0) mism = 0;
    __syncthreads();   // all ctv reads done; safe to overwrite msg

    const size_t BN = (size_t)B * NV;
#pragma unroll
    for (int k = 0; k < VPT; ++k) {
        const int v = t + k * BLOCK;
        out[(size_t)b * NV + v]      = marg[k];        // output 0: marginals
        out[BN + (size_t)b * NV + v] = hard[k];        // output 1: hard_decision
        const float h = hard[k];                       // scatter hard bit to edges
        *(float*)(mb + vsB[k][0]) = h;
        *(float*)(mb + vsB[k][1]) = h;
        *(float*)(mb + vsB[k][2]) = h;
        *(float*)(mb + vsB[k][3]) = h;
    }
    __syncthreads();

    // syn_hat[c] = parity over the check's edges' hard bits; converged iff == syndrome
#pragma unroll
    for (int k = 0; k < CPT; ++k) {
        const int d  = dsb[k] >> 1;
        const int sb = dsb[k] & 1;
        int par = 0;
        for (int j = 0; j < d; ++j)
            par ^= (*(const float*)(mb + cstB[k] + 4 * j) != 0.0f) ? 1 : 0;
        if (par != sb) mism = 1;   // benign race: all writers store 1
    }
    __syncthreads();
    if (t == 0) out[2 * BN + b] = mism ? 0.0f : 1.0f;  // output 2: converged
}

extern "C" void kernel_launch(void* const* d_in, const int* in_sizes, int n_in,
                              void* d_out, int out_size, void* d_ws, size_t ws_size,
                              hipStream_t stream) {
    const float* syndrome   = (const float*)d_in[0];
    const float* llr        = (const float*)d_in[1];
    const int*   var_adj    = (const int*)d_in[2];
    // d_in[3] var_adj_mask: all ones (DV=4 exact) — unused
    const int*   check_adj  = (const int*)d_in[4];
    const float* check_mask = (const float*)d_in[5];
    const int*   var_idx    = (const int*)d_in[6];
    // d_in[7] pcm_dense — unused
    float* out = (float*)d_out;
    int*   ws  = (int*)d_ws;    // needs 2*MC ints = 32 KB (proven size)

    const int B      = in_sizes[0] / MC;      // 256
    const int max_dc = in_sizes[4] / MC;

    setup_sort<<<1, BLOCK, 0, stream>>>(check_mask, check_adj, max_dc, ws);
    bp_decode<<<B, BLOCK, 0, stream>>>(syndrome, llr, var_adj, var_idx,
                                       check_adj, max_dc, ws, out, B);
}